// Round 7
// baseline (135.251 us; speedup 1.0000x reference)
//
#include <hip/hip_runtime.h>
#include <math.h>

constexpr int NN = 32768;   // nodes
constexpr int SS = 32768;   // subgraph-node entries
constexpr int CC = 1024;    // clusters
constexpr int EE = 16384;   // coarsen edges
constexpr int BB = 16;      // graphs
constexpr int PP = 64;      // patches per graph
constexpr int NC = 10;      // classes

__device__ __forceinline__ float rdlane(float v, int l) {
    return __int_as_float(__builtin_amdgcn_readlane(__float_as_int(v), l));
}

// ---------------------------------------------------------------------------
// k_graph: ALL edge/segment preprocessing in one single-block kernel.
// deg/rowcnt/rowfill live in LDS only. E = 16 * 1024 exactly.
//   outputs: segoff[C+1], rowptr[C+1], colS[E], eawS[E] (CSR order)
// ---------------------------------------------------------------------------
__global__ __launch_bounds__(1024) void k_graph(
    const int* __restrict__ row, const int* __restrict__ col,
    const float* __restrict__ attr, const int* __restrict__ batch,
    int* __restrict__ segoff, int* __restrict__ rowptr,
    int* __restrict__ colS, float* __restrict__ eawS)
{
    __shared__ float ldeg[1024];
    __shared__ int lcnt[1024];
    __shared__ int lscan[1024];
    __shared__ int lfill[1024];
    int tid = threadIdx.x;
    ldeg[tid] = 0.f; lcnt[tid] = 0;
    __syncthreads();
#pragma unroll
    for (int i = 0; i < 16; ++i) {
        int e = i * 1024 + tid;
        int r = row[e];
        atomicAdd(&ldeg[r], attr[e]);
        atomicAdd(&lcnt[r], 1);
    }
    __syncthreads();
    int v = lcnt[tid];
    lscan[tid] = v;
    __syncthreads();
    for (int off = 1; off < 1024; off <<= 1) {
        int t = (tid >= off) ? lscan[tid - off] : 0;
        __syncthreads();
        lscan[tid] += t;
        __syncthreads();
    }
    int incl = lscan[tid];
    if (tid == 0) rowptr[0] = 0;
    rowptr[tid + 1] = incl;
    lfill[tid] = incl - v;     // exclusive prefix = fill cursor
    // segoff: lower_bound of sorted batch
    int lo = 0, hi = SS;
    while (lo < hi) { int mid = (lo + hi) >> 1; if (batch[mid] < tid) lo = mid + 1; else hi = mid; }
    segoff[tid] = lo;
    if (tid == 0) segoff[CC] = SS;
    __syncthreads();
#pragma unroll
    for (int i = 0; i < 16; ++i) {
        int e = i * 1024 + tid;
        int r = row[e], c = col[e];
        float dr = ldeg[r], dc = ldeg[c];
        float ir = dr > 0.f ? 1.f / sqrtf(dr) : 0.f;
        float ic = dc > 0.f ? 1.f / sqrtf(dc) : 0.f;
        int pos = atomicAdd(&lfill[r], 1);
        colS[pos] = c;
        eawS[pos] = ir * attr[e] * ic;
    }
}

// ---------------------------------------------------------------------------
// k_node: fused per-node dense chain, register-prefetched weight staging.
//   t1 = relu(x@W1+b1); h = relu(t1@W2+b2); u = relu(h@Wp1+bp1) -> u
//   K = h@WK+bK, V = h@WV+bV (dual) -> KV
// One __syncthreads per phase; next phase's weights loaded to regs during
// current GEMM, written to the alternate LDS buffer after. Also zeros H/den.
// ---------------------------------------------------------------------------
#define TS 68

__device__ __forceinline__ void gemm64(const float* A, const float* W,
                                       const float* __restrict__ bias,
                                       int r0, int c0, float acc[4][4])
{
#pragma unroll
    for (int dc = 0; dc < 4; ++dc) {
        float bv = bias[c0 + dc];
        acc[0][dc] = bv; acc[1][dc] = bv; acc[2][dc] = bv; acc[3][dc] = bv;
    }
#pragma unroll 16
    for (int k = 0; k < 64; ++k) {
        float4 av = *(const float4*)(A + k * TS + r0);
        float4 wv = *(const float4*)(W + k * TS + c0);
        acc[0][0] = fmaf(av.x, wv.x, acc[0][0]); acc[0][1] = fmaf(av.x, wv.y, acc[0][1]);
        acc[0][2] = fmaf(av.x, wv.z, acc[0][2]); acc[0][3] = fmaf(av.x, wv.w, acc[0][3]);
        acc[1][0] = fmaf(av.y, wv.x, acc[1][0]); acc[1][1] = fmaf(av.y, wv.y, acc[1][1]);
        acc[1][2] = fmaf(av.y, wv.z, acc[1][2]); acc[1][3] = fmaf(av.y, wv.w, acc[1][3]);
        acc[2][0] = fmaf(av.z, wv.x, acc[2][0]); acc[2][1] = fmaf(av.z, wv.y, acc[2][1]);
        acc[2][2] = fmaf(av.z, wv.z, acc[2][2]); acc[2][3] = fmaf(av.z, wv.w, acc[2][3]);
        acc[3][0] = fmaf(av.w, wv.x, acc[3][0]); acc[3][1] = fmaf(av.w, wv.y, acc[3][1]);
        acc[3][2] = fmaf(av.w, wv.z, acc[3][2]); acc[3][3] = fmaf(av.w, wv.w, acc[3][3]);
    }
}

__device__ __forceinline__ void gemm64x2(const float* A, const float* Wa, const float* Wb,
                                         const float* __restrict__ bias1,
                                         const float* __restrict__ bias2,
                                         int r0, int c0, float acc1[4][4], float acc2[4][4])
{
#pragma unroll
    for (int dc = 0; dc < 4; ++dc) {
        float bv1 = bias1[c0 + dc], bv2 = bias2[c0 + dc];
#pragma unroll
        for (int dr = 0; dr < 4; ++dr) { acc1[dr][dc] = bv1; acc2[dr][dc] = bv2; }
    }
#pragma unroll 8
    for (int k = 0; k < 64; ++k) {
        float4 av = *(const float4*)(A + k * TS + r0);
        float4 w1 = *(const float4*)(Wa + k * TS + c0);
        float4 w2 = *(const float4*)(Wb + k * TS + c0);
        float ar[4] = {av.x, av.y, av.z, av.w};
        float u1[4] = {w1.x, w1.y, w1.z, w1.w};
        float u2[4] = {w2.x, w2.y, w2.z, w2.w};
#pragma unroll
        for (int dr = 0; dr < 4; ++dr)
#pragma unroll
            for (int dc = 0; dc < 4; ++dc) {
                acc1[dr][dc] = fmaf(ar[dr], u1[dc], acc1[dr][dc]);
                acc2[dr][dc] = fmaf(ar[dr], u2[dc], acc2[dr][dc]);
            }
    }
}

// write 16 weight floats (4xfloat4, element idx = tid*4 + t*1024) to LDS [k][col]
__device__ __forceinline__ void writeW(float* dst, int tid,
                                       float4 a, float4 b, float4 c, float4 d)
{
    int colq = (tid & 15) * 4;
    int rb = tid >> 4;
    *(float4*)(dst + (rb     ) * TS + colq) = a;
    *(float4*)(dst + (rb + 16) * TS + colq) = b;
    *(float4*)(dst + (rb + 32) * TS + colq) = c;
    *(float4*)(dst + (rb + 48) * TS + colq) = d;
}

// write 16 x floats transposed: element idx -> dst[(idx&63)*TS + (idx>>6)]
__device__ __forceinline__ void writeXT(float* dst, int tid,
                                        float4 a, float4 b, float4 c, float4 d)
{
    int rb = (tid * 4) & 63;
    int cb = tid >> 4;
    dst[(rb + 0) * TS + cb     ] = a.x;
    dst[(rb + 1) * TS + cb     ] = a.y;
    dst[(rb + 2) * TS + cb     ] = a.z;
    dst[(rb + 3) * TS + cb     ] = a.w;
    dst[(rb + 0) * TS + cb + 16] = b.x;
    dst[(rb + 1) * TS + cb + 16] = b.y;
    dst[(rb + 2) * TS + cb + 16] = b.z;
    dst[(rb + 3) * TS + cb + 16] = b.w;
    dst[(rb + 0) * TS + cb + 32] = c.x;
    dst[(rb + 1) * TS + cb + 32] = c.y;
    dst[(rb + 2) * TS + cb + 32] = c.z;
    dst[(rb + 3) * TS + cb + 32] = c.w;
    dst[(rb + 0) * TS + cb + 48] = d.x;
    dst[(rb + 1) * TS + cb + 48] = d.y;
    dst[(rb + 2) * TS + cb + 48] = d.z;
    dst[(rb + 3) * TS + cb + 48] = d.w;
}

__device__ __forceinline__ void outT_relu(float* dst, int r0, int c0, float acc[4][4])
{
#pragma unroll
    for (int dc = 0; dc < 4; ++dc) {
        *(float4*)(dst + (c0 + dc) * TS + r0) =
            make_float4(fmaxf(acc[0][dc], 0.f), fmaxf(acc[1][dc], 0.f),
                        fmaxf(acc[2][dc], 0.f), fmaxf(acc[3][dc], 0.f));
    }
}

__device__ __forceinline__ void outG2(float* __restrict__ dst, size_t rowbase, int ld,
                                      int off, int r0, int c0, float acc[4][4], bool dorelu)
{
#pragma unroll
    for (int dr = 0; dr < 4; ++dr) {
        float4 v = make_float4(acc[dr][0], acc[dr][1], acc[dr][2], acc[dr][3]);
        if (dorelu) {
            v.x = fmaxf(v.x, 0.f); v.y = fmaxf(v.y, 0.f);
            v.z = fmaxf(v.z, 0.f); v.w = fmaxf(v.w, 0.f);
        }
        *(float4*)(dst + (rowbase + r0 + dr) * ld + off + c0) = v;
    }
}

__global__ __launch_bounds__(256, 2) void k_node(
    const float* __restrict__ x,
    const float* __restrict__ W1, const float* __restrict__ b1,
    const float* __restrict__ W2, const float* __restrict__ b2,
    const float* __restrict__ Wp1, const float* __restrict__ bp1,
    const float* __restrict__ WK, const float* __restrict__ bK,
    const float* __restrict__ WV, const float* __restrict__ bV,
    float* __restrict__ u, float* __restrict__ KV, float* __restrict__ zbase)
{
    __shared__ __align__(16) float bufA[64 * TS];
    __shared__ __align__(16) float bufB[64 * TS];
    __shared__ __align__(16) float w0[64 * TS];
    __shared__ __align__(16) float w1[64 * TS];
    int tid = threadIdx.x;
    // zero H/den: 16640 float4 across 512 blocks (33 each, guarded)
    if (tid < 33) {
        int i = blockIdx.x * 33 + tid;
        if (i < 16640) ((float4*)zbase)[i] = make_float4(0.f, 0.f, 0.f, 0.f);
    }
    int tx = tid & 15, ty = tid >> 4;
    int r0 = ty * 4, c0 = tx * 4;
    size_t rowbase = (size_t)blockIdx.x * 64;
    const float* xb = x + rowbase * 64;
    // prologue: W1 + x to regs, then LDS
    float4 a0 = ((const float4*)W1)[tid];
    float4 a1 = ((const float4*)W1)[tid + 256];
    float4 a2 = ((const float4*)W1)[tid + 512];
    float4 a3 = ((const float4*)W1)[tid + 768];
    float4 x0 = ((const float4*)xb)[tid];
    float4 x1 = ((const float4*)xb)[tid + 256];
    float4 x2 = ((const float4*)xb)[tid + 512];
    float4 x3 = ((const float4*)xb)[tid + 768];
    writeW(w0, tid, a0, a1, a2, a3);
    writeXT(bufA, tid, x0, x1, x2, x3);
    __syncthreads();
    float acc[4][4], accV[4][4];
    // P0: t1 = relu(x@W1+b1) -> bufB ; prefetch W2 -> w1
    a0 = ((const float4*)W2)[tid];
    a1 = ((const float4*)W2)[tid + 256];
    a2 = ((const float4*)W2)[tid + 512];
    a3 = ((const float4*)W2)[tid + 768];
    gemm64(bufA, w0, b1, r0, c0, acc);
    outT_relu(bufB, r0, c0, acc);
    writeW(w1, tid, a0, a1, a2, a3);
    __syncthreads();
    // P1: h = relu(t1@W2+b2) -> bufA ; prefetch Wp1 -> w0
    a0 = ((const float4*)Wp1)[tid];
    a1 = ((const float4*)Wp1)[tid + 256];
    a2 = ((const float4*)Wp1)[tid + 512];
    a3 = ((const float4*)Wp1)[tid + 768];
    gemm64(bufB, w1, b2, r0, c0, acc);
    outT_relu(bufA, r0, c0, acc);
    writeW(w0, tid, a0, a1, a2, a3);
    __syncthreads();
    // P2: u = relu(h@Wp1+bp1) -> global ; prefetch WK -> w1, WV -> bufB (dead)
    a0 = ((const float4*)WK)[tid];
    a1 = ((const float4*)WK)[tid + 256];
    a2 = ((const float4*)WK)[tid + 512];
    a3 = ((const float4*)WK)[tid + 768];
    float4 v0 = ((const float4*)WV)[tid];
    float4 v1 = ((const float4*)WV)[tid + 256];
    float4 v2 = ((const float4*)WV)[tid + 512];
    float4 v3 = ((const float4*)WV)[tid + 768];
    gemm64(bufA, w0, bp1, r0, c0, acc);
    outG2(u, rowbase, 64, 0, r0, c0, acc, true);
    writeW(w1, tid, a0, a1, a2, a3);
    writeW(bufB, tid, v0, v1, v2, v3);
    __syncthreads();
    // P3: K = h@WK+bK, V = h@WV+bV -> KV
    gemm64x2(bufA, w1, bufB, bK, bV, r0, c0, acc, accV);
    outG2(KV, rowbase, 128, 0, r0, c0, acc, false);
    outG2(KV, rowbase, 128, 64, r0, c0, accV, false);
}

// ---------------------------------------------------------------------------
// k_msb: block per cluster. K/V chunks staged in LDS; GEMM encoding builds
// Msb[c] = relu(K)^T @ V; also Ksk/Krsum/Vsum/Lf and the full Q path -> Qk.
// ---------------------------------------------------------------------------
#define KSTR 72

__global__ __launch_bounds__(256, 4) void k_msb(
    const float* __restrict__ u, const float* __restrict__ KV,
    const int* __restrict__ mapper, const int* __restrict__ segoff,
    const float* __restrict__ Wp2, const float* __restrict__ bp2,
    const float* __restrict__ Wpo1, const float* __restrict__ bpo1,
    const float* __restrict__ Wpo2, const float* __restrict__ bpo2,
    float* __restrict__ Msb, float* __restrict__ Qk, float* __restrict__ Ksk,
    float* __restrict__ Krsum, float* __restrict__ Vsum, float* __restrict__ Lf)
{
    __shared__ __align__(16) float Kr[32 * KSTR];
    __shared__ __align__(16) float Vb[32 * KSTR];
    __shared__ int map_lds[32];
    __shared__ float sums[256];
    __shared__ float redu0[64], redu1[64], redu2[64];
    int c = blockIdx.x;
    int tid = threadIdx.x, j = tid & 63, g = tid >> 6;
    int tx = tid & 15, ty = tid >> 4;
    int r0 = ty * 4, c0 = tx * 4;
    int s0 = segoff[c], s1 = segoff[c + 1];
    sums[tid] = 0.f;
    float acc[4][4];
#pragma unroll
    for (int a = 0; a < 4; ++a)
#pragma unroll
        for (int b = 0; b < 4; ++b) acc[a][b] = 0.f;
    float qs = 0.f, ks = 0.f, krs = 0.f, vs = 0.f;
    __syncthreads();
    for (int sb = s0; sb < s1; sb += 32) {
        int clen = min(32, s1 - sb);
        __syncthreads();
        if (tid < clen) map_lds[tid] = mapper[sb + tid];
        __syncthreads();
        for (int p = tid; p < clen * 32; p += 256) {
            int e = p >> 5, q = p & 31;
            int m = map_lds[e];
            float4 v = *(const float4*)(KV + (size_t)m * 128 + q * 4);
            float* dst = (q < 16) ? &Kr[e * KSTR + q * 4] : &Vb[e * KSTR + (q - 16) * 4];
            *(float4*)dst = v;
        }
        __syncthreads();
#pragma unroll 4
        for (int s = 0; s < clen; ++s) {
            float4 a4 = *(const float4*)(&Kr[s * KSTR + r0]);
            float4 b4 = *(const float4*)(&Vb[s * KSTR + c0]);
            float ar0 = fmaxf(a4.x, 0.f), ar1 = fmaxf(a4.y, 0.f);
            float ar2 = fmaxf(a4.z, 0.f), ar3 = fmaxf(a4.w, 0.f);
            acc[0][0] = fmaf(ar0, b4.x, acc[0][0]); acc[0][1] = fmaf(ar0, b4.y, acc[0][1]);
            acc[0][2] = fmaf(ar0, b4.z, acc[0][2]); acc[0][3] = fmaf(ar0, b4.w, acc[0][3]);
            acc[1][0] = fmaf(ar1, b4.x, acc[1][0]); acc[1][1] = fmaf(ar1, b4.y, acc[1][1]);
            acc[1][2] = fmaf(ar1, b4.z, acc[1][2]); acc[1][3] = fmaf(ar1, b4.w, acc[1][3]);
            acc[2][0] = fmaf(ar2, b4.x, acc[2][0]); acc[2][1] = fmaf(ar2, b4.y, acc[2][1]);
            acc[2][2] = fmaf(ar2, b4.z, acc[2][2]); acc[2][3] = fmaf(ar2, b4.w, acc[2][3]);
            acc[3][0] = fmaf(ar3, b4.x, acc[3][0]); acc[3][1] = fmaf(ar3, b4.y, acc[3][1]);
            acc[3][2] = fmaf(ar3, b4.z, acc[3][2]); acc[3][3] = fmaf(ar3, b4.w, acc[3][3]);
        }
        for (int s = g; s < clen; s += 4) {
            float kv = Kr[s * KSTR + j];
            ks += kv;
            krs += fmaxf(kv, 0.f);
            vs += Vb[s * KSTR + j];
            qs += u[(size_t)map_lds[s] * 64 + j];
        }
    }
    atomicAdd(&sums[j], qs);
    atomicAdd(&sums[64 + j], ks);
    atomicAdd(&sums[128 + j], krs);
    atomicAdd(&sums[192 + j], vs);
    size_t mb = (size_t)c * 4096;
#pragma unroll
    for (int a = 0; a < 4; ++a)
        *(float4*)(Msb + mb + (size_t)(r0 + a) * 64 + c0) =
            make_float4(acc[a][0], acc[a][1], acc[a][2], acc[a][3]);
    int L = s1 - s0;
    if (tid < 64) {
        redu0[tid] = (float)L * bp2[tid];
        redu1[tid] = bpo1[tid];
        redu2[tid] = bpo2[tid];
    }
    __syncthreads();
    float qsv = sums[j];
    float Lm = (float)(L > 0 ? L : 1);
    if (g == 0) {
        Ksk[c * 64 + j] = fmaxf(sums[64 + j] / Lm, 0.f);
        Krsum[c * 64 + j] = sums[128 + j];
        Vsum[c * 64 + j] = sums[192 + j];
        if (j == 0) Lf[c] = (float)L;
    }
    float p = 0.f;
#pragma unroll
    for (int t = 0; t < 16; ++t) {
        int i = g * 16 + t;
        p = fmaf(rdlane(qsv, i), Wp2[i * 64 + j], p);
    }
    atomicAdd(&redu0[j], p);
    __syncthreads();
    float q2 = redu0[j];
    p = 0.f;
#pragma unroll
    for (int t = 0; t < 16; ++t) {
        int i = g * 16 + t;
        p = fmaf(rdlane(q2, i), Wpo1[i * 64 + j], p);
    }
    atomicAdd(&redu1[j], p);
    __syncthreads();
    float tt = fmaxf(redu1[j], 0.f);
    p = 0.f;
#pragma unroll
    for (int t = 0; t < 16; ++t) {
        int i = g * 16 + t;
        p = fmaf(rdlane(tt, i), Wpo2[i * 64 + j], p);
    }
    atomicAdd(&redu2[j], p);
    __syncthreads();
    if (tid < 64) Qk[c * 64 + tid] = fmaxf(redu2[tid], 0.f);
}

// ---------------------------------------------------------------------------
// k_edges: block per source r; Msb[r] staged once into LDS (stride 68);
// 4 waves edge-parallel; no per-thread arrays.
// ---------------------------------------------------------------------------
#define MSTR 68

__global__ __launch_bounds__(256, 4) void k_edges(
    const float* __restrict__ Msb, const float* __restrict__ Qk,
    const float* __restrict__ Ksk, const float* __restrict__ Krsum,
    const float* __restrict__ Vsum, const float* __restrict__ Lf,
    const float* __restrict__ eawS, const int* __restrict__ colS,
    const int* __restrict__ rowptr, const float* __restrict__ ab,
    float* __restrict__ H, float* __restrict__ den)
{
    __shared__ __align__(16) float msb[64 * MSTR];
    int r = blockIdx.x;
    int e0 = rowptr[r], e1 = rowptr[r + 1];
    if (e0 == e1) return;
    int tid = threadIdx.x, j = tid & 63, g = tid >> 6;
    size_t mb = (size_t)r * 4096;
    for (int p = tid; p < 1024; p += 256) {
        float4 v = *(const float4*)(Msb + mb + (size_t)p * 4);
        int i = p >> 4, j0 = (p & 15) * 4;
        *(float4*)(&msb[i * MSTR + j0]) = v;
    }
    float kskj = Ksk[r * 64 + j];
    float krj  = Krsum[r * 64 + j];
    float vsj  = Vsum[r * 64 + j];
    float Lr   = Lf[r];
    float a0 = ab[0], a1 = ab[1];
    float sa2 = 1.f + expf(a1 - a0);
    float sb2 = 1.f + expf(a0 - a1);
    __syncthreads();
    int idx = e0 + g;
    if (idx >= e1) return;
    int c = colS[idx];
    float w = eawS[idx];
    float qv = Qk[c * 64 + j];
    while (true) {
        int cc = c; float wc = w, qc = qv;
        int nidx = idx + 4;
        if (nidx < e1) {
            c = colS[nidx];
            w = eawS[nidx];
            qv = Qk[c * 64 + j];
        }
        float wj0 = 0.f, wj1 = 0.f, wj2 = 0.f, wj3 = 0.f;
#pragma unroll
        for (int t = 0; t < 16; ++t) {
            wj0 = fmaf(rdlane(qc, 4 * t + 0), msb[(4 * t + 0) * MSTR + j], wj0);
            wj1 = fmaf(rdlane(qc, 4 * t + 1), msb[(4 * t + 1) * MSTR + j], wj1);
            wj2 = fmaf(rdlane(qc, 4 * t + 2), msb[(4 * t + 2) * MSTR + j], wj2);
            wj3 = fmaf(rdlane(qc, 4 * t + 3), msb[(4 * t + 3) * MSTR + j], wj3);
        }
        float wjt = (wj0 + wj1) + (wj2 + wj3);
        float p1 = qc * kskj;
        float p2 = qc * krj;
#pragma unroll
        for (int o = 32; o > 0; o >>= 1) { p1 += __shfl_xor(p1, o); p2 += __shfl_xor(p2, o); }
        atomicAdd(&H[cc * 64 + j], wc * (sb2 * wjt + sa2 * p1 * vsj));
        if (j == 0) atomicAdd(&den[cc], wc * (sa2 * Lr * p1 + sb2 * p2));
        idx = nidx;
        if (idx >= e1) break;
    }
}

// ---------------------------------------------------------------------------
__global__ __launch_bounds__(64) void k_final(
    const float* __restrict__ H, const float* __restrict__ den,
    const float* __restrict__ Wc1, const float* __restrict__ bc1,
    const float* __restrict__ Wc2, const float* __restrict__ bc2,
    float* __restrict__ out)
{
    int bg = blockIdx.x;
    int j = threadIdx.x;
    float acc = 0.f;
    for (int p = 0; p < PP; ++p) {
        int c = bg * PP + p;
        acc += H[c * 64 + j] / (den[c] + 1e-6f);
    }
    float g = acc * (1.f / (float)PP);
    int m = j & 31;
    float a1 = bc1[m];
#pragma unroll
    for (int i = 0; i < 64; ++i) a1 = fmaf(rdlane(g, i), Wc1[i * 32 + m], a1);
    float c1 = fmaxf(a1, 0.f);
    int n = (j < NC) ? j : 0;
    float a2 = bc2[n];
#pragma unroll
    for (int i = 0; i < 32; ++i) a2 = fmaf(rdlane(c1, i), Wc2[i * NC + n], a2);
    if (j < NC) out[bg * NC + j] = a2;
}

// ---------------------------------------------------------------------------
extern "C" void kernel_launch(void* const* d_in, const int* in_sizes, int n_in,
                              void* d_out, int out_size, void* d_ws, size_t ws_size,
                              hipStream_t stream)
{
    const float* x      = (const float*)d_in[0];
    const int*   mapper = (const int*)d_in[1];
    const int*   batch  = (const int*)d_in[2];
    const int*   row    = (const int*)d_in[3];
    const int*   col    = (const int*)d_in[4];
    const float* attr   = (const float*)d_in[5];
    const float* W_in1  = (const float*)d_in[6];
    const float* b_in1  = (const float*)d_in[7];
    const float* W_in2  = (const float*)d_in[8];
    const float* b_in2  = (const float*)d_in[9];
    const float* W_pre1 = (const float*)d_in[10];
    const float* b_pre1 = (const float*)d_in[11];
    const float* W_pre2 = (const float*)d_in[12];
    const float* b_pre2 = (const float*)d_in[13];
    const float* W_post1= (const float*)d_in[14];
    const float* b_post1= (const float*)d_in[15];
    const float* W_post2= (const float*)d_in[16];
    const float* b_post2= (const float*)d_in[17];
    const float* W_K    = (const float*)d_in[18];
    const float* b_K    = (const float*)d_in[19];
    const float* W_V    = (const float*)d_in[20];
    const float* b_V    = (const float*)d_in[21];
    const float* alpha_beta = (const float*)d_in[22];
    const float* W_c1   = (const float*)d_in[23];
    const float* b_c1   = (const float*)d_in[24];
    const float* W_c2   = (const float*)d_in[25];
    const float* b_c2   = (const float*)d_in[26];

    float* ws = (float*)d_ws;
    float* u     = ws;                        // N*64
    float* KV    = u     + (size_t)NN * 64;   // N*128
    float* Qk    = KV    + (size_t)NN * 128;  // C*64
    float* eawS  = Qk    + (size_t)CC * 64;   // E (CSR order)
    float* Msb   = eawS  + (size_t)EE;        // C*4096
    float* Ksk   = Msb   + (size_t)CC * 4096; // C*64
    float* Krsum = Ksk   + (size_t)CC * 64;   // C*64
    float* Vsum  = Krsum + (size_t)CC * 64;   // C*64
    float* Lf    = Vsum  + (size_t)CC * 64;   // C
    // --- zeroed by k_node: H (C*64) + den (C) = 66560 floats = 16640 float4 ---
    float* H     = Lf    + (size_t)CC;        // C*64
    float* den   = H     + (size_t)CC * 64;   // C
    // --- int region ---
    int*  segoff = (int*)(den + (size_t)CC);  // C+1
    int*  rowptr = segoff + (CC + 1);         // C+1
    int*  colS   = rowptr + (CC + 1);         // E (CSR order)

    k_graph<<<1, 1024, 0, stream>>>(row, col, attr, batch, segoff, rowptr, colS, eawS);
    k_node<<<NN / 64, 256, 0, stream>>>(x, W_in1, b_in1, W_in2, b_in2,
                                        W_pre1, b_pre1, W_K, b_K, W_V, b_V, u, KV, H);
    k_msb<<<CC, 256, 0, stream>>>(u, KV, mapper, segoff,
                                  W_pre2, b_pre2, W_post1, b_post1,
                                  W_post2, b_post2,
                                  Msb, Qk, Ksk, Krsum, Vsum, Lf);
    k_edges<<<CC, 256, 0, stream>>>(Msb, Qk, Ksk, Krsum, Vsum, Lf, eawS, colS,
                                    rowptr, alpha_beta, H, den);
    k_final<<<BB, 64, 0, stream>>>(H, den, W_c1, b_c1, W_c2, b_c2, (float*)d_out);
}

// Round 8
// 107.009 us; speedup vs baseline: 1.2639x; 1.2639x over previous
//
#include <hip/hip_runtime.h>
#include <math.h>

constexpr int NN = 32768;   // nodes
constexpr int SS = 32768;   // subgraph-node entries
constexpr int CC = 1024;    // clusters
constexpr int EE = 16384;   // coarsen edges
constexpr int BB = 16;      // graphs
constexpr int PP = 64;      // patches per graph
constexpr int NC = 10;      // classes

__device__ __forceinline__ float rdlane(float v, int l) {
    return __int_as_float(__builtin_amdgcn_readlane(__float_as_int(v), l));
}

// ---------------------------------------------------------------------------
// k_degseg: wide preprocessing, one launch, no global atomics, no zeroing.
//  blocks 0..63  : deg for rows [16b,16b+16) — LDS-accumulate over edge stream
//  blocks 64..191: segoff boundary writes over sorted batch (t covers SS)
// ---------------------------------------------------------------------------
__global__ __launch_bounds__(256) void k_degseg(
    const int* __restrict__ row, const float* __restrict__ attr,
    const int* __restrict__ batch,
    float* __restrict__ deg, int* __restrict__ segoff)
{
    int b = blockIdx.x;
    int tid = threadIdx.x;
    if (b < 64) {
        __shared__ float ldeg[16];
        if (tid < 16) ldeg[tid] = 0.f;
        __syncthreads();
        int lo = b * 16;
#pragma unroll 4
        for (int i = 0; i < 64; ++i) {
            int e = i * 256 + tid;
            int r = row[e];
            unsigned d = (unsigned)(r - lo);
            if (d < 16u) atomicAdd(&ldeg[d], attr[e]);
        }
        __syncthreads();
        if (tid < 16) deg[lo + tid] = ldeg[tid];
    } else {
        int t = (b - 64) * 256 + tid;          // covers [0, SS)
        int cur = batch[t];
        int prev = (t == 0) ? -1 : batch[t - 1];
        for (int c = prev + 1; c <= cur; ++c) segoff[c] = t;
        if (t == SS - 1)
            for (int c = cur + 1; c <= CC; ++c) segoff[c] = SS;
    }
}

// ---------------------------------------------------------------------------
// k_node: fused per-node dense chain, register-prefetched weight staging.
//   t1 = relu(x@W1+b1); h = relu(t1@W2+b2); u = relu(h@Wp1+bp1) -> u
//   K = h@WK+bK, V = h@WV+bV (dual) -> KV.  Also zeros H/den.
// ---------------------------------------------------------------------------
#define TS 68

__device__ __forceinline__ void gemm64(const float* A, const float* W,
                                       const float* __restrict__ bias,
                                       int r0, int c0, float acc[4][4])
{
#pragma unroll
    for (int dc = 0; dc < 4; ++dc) {
        float bv = bias[c0 + dc];
        acc[0][dc] = bv; acc[1][dc] = bv; acc[2][dc] = bv; acc[3][dc] = bv;
    }
#pragma unroll 16
    for (int k = 0; k < 64; ++k) {
        float4 av = *(const float4*)(A + k * TS + r0);
        float4 wv = *(const float4*)(W + k * TS + c0);
        acc[0][0] = fmaf(av.x, wv.x, acc[0][0]); acc[0][1] = fmaf(av.x, wv.y, acc[0][1]);
        acc[0][2] = fmaf(av.x, wv.z, acc[0][2]); acc[0][3] = fmaf(av.x, wv.w, acc[0][3]);
        acc[1][0] = fmaf(av.y, wv.x, acc[1][0]); acc[1][1] = fmaf(av.y, wv.y, acc[1][1]);
        acc[1][2] = fmaf(av.y, wv.z, acc[1][2]); acc[1][3] = fmaf(av.y, wv.w, acc[1][3]);
        acc[2][0] = fmaf(av.z, wv.x, acc[2][0]); acc[2][1] = fmaf(av.z, wv.y, acc[2][1]);
        acc[2][2] = fmaf(av.z, wv.z, acc[2][2]); acc[2][3] = fmaf(av.z, wv.w, acc[2][3]);
        acc[3][0] = fmaf(av.w, wv.x, acc[3][0]); acc[3][1] = fmaf(av.w, wv.y, acc[3][1]);
        acc[3][2] = fmaf(av.w, wv.z, acc[3][2]); acc[3][3] = fmaf(av.w, wv.w, acc[3][3]);
    }
}

__device__ __forceinline__ void gemm64x2(const float* A, const float* Wa, const float* Wb,
                                         const float* __restrict__ bias1,
                                         const float* __restrict__ bias2,
                                         int r0, int c0, float acc1[4][4], float acc2[4][4])
{
#pragma unroll
    for (int dc = 0; dc < 4; ++dc) {
        float bv1 = bias1[c0 + dc], bv2 = bias2[c0 + dc];
#pragma unroll
        for (int dr = 0; dr < 4; ++dr) { acc1[dr][dc] = bv1; acc2[dr][dc] = bv2; }
    }
#pragma unroll 8
    for (int k = 0; k < 64; ++k) {
        float4 av = *(const float4*)(A + k * TS + r0);
        float4 w1 = *(const float4*)(Wa + k * TS + c0);
        float4 w2 = *(const float4*)(Wb + k * TS + c0);
        float ar[4] = {av.x, av.y, av.z, av.w};
        float u1[4] = {w1.x, w1.y, w1.z, w1.w};
        float u2[4] = {w2.x, w2.y, w2.z, w2.w};
#pragma unroll
        for (int dr = 0; dr < 4; ++dr)
#pragma unroll
            for (int dc = 0; dc < 4; ++dc) {
                acc1[dr][dc] = fmaf(ar[dr], u1[dc], acc1[dr][dc]);
                acc2[dr][dc] = fmaf(ar[dr], u2[dc], acc2[dr][dc]);
            }
    }
}

__device__ __forceinline__ void writeW(float* dst, int tid,
                                       float4 a, float4 b, float4 c, float4 d)
{
    int colq = (tid & 15) * 4;
    int rb = tid >> 4;
    *(float4*)(dst + (rb     ) * TS + colq) = a;
    *(float4*)(dst + (rb + 16) * TS + colq) = b;
    *(float4*)(dst + (rb + 32) * TS + colq) = c;
    *(float4*)(dst + (rb + 48) * TS + colq) = d;
}

__device__ __forceinline__ void writeXT(float* dst, int tid,
                                        float4 a, float4 b, float4 c, float4 d)
{
    int rb = (tid * 4) & 63;
    int cb = tid >> 4;
    dst[(rb + 0) * TS + cb     ] = a.x;
    dst[(rb + 1) * TS + cb     ] = a.y;
    dst[(rb + 2) * TS + cb     ] = a.z;
    dst[(rb + 3) * TS + cb     ] = a.w;
    dst[(rb + 0) * TS + cb + 16] = b.x;
    dst[(rb + 1) * TS + cb + 16] = b.y;
    dst[(rb + 2) * TS + cb + 16] = b.z;
    dst[(rb + 3) * TS + cb + 16] = b.w;
    dst[(rb + 0) * TS + cb + 32] = c.x;
    dst[(rb + 1) * TS + cb + 32] = c.y;
    dst[(rb + 2) * TS + cb + 32] = c.z;
    dst[(rb + 3) * TS + cb + 32] = c.w;
    dst[(rb + 0) * TS + cb + 48] = d.x;
    dst[(rb + 1) * TS + cb + 48] = d.y;
    dst[(rb + 2) * TS + cb + 48] = d.z;
    dst[(rb + 3) * TS + cb + 48] = d.w;
}

__device__ __forceinline__ void outT_relu(float* dst, int r0, int c0, float acc[4][4])
{
#pragma unroll
    for (int dc = 0; dc < 4; ++dc) {
        *(float4*)(dst + (c0 + dc) * TS + r0) =
            make_float4(fmaxf(acc[0][dc], 0.f), fmaxf(acc[1][dc], 0.f),
                        fmaxf(acc[2][dc], 0.f), fmaxf(acc[3][dc], 0.f));
    }
}

__device__ __forceinline__ void outG2(float* __restrict__ dst, size_t rowbase, int ld,
                                      int off, int r0, int c0, float acc[4][4], bool dorelu)
{
#pragma unroll
    for (int dr = 0; dr < 4; ++dr) {
        float4 v = make_float4(acc[dr][0], acc[dr][1], acc[dr][2], acc[dr][3]);
        if (dorelu) {
            v.x = fmaxf(v.x, 0.f); v.y = fmaxf(v.y, 0.f);
            v.z = fmaxf(v.z, 0.f); v.w = fmaxf(v.w, 0.f);
        }
        *(float4*)(dst + (rowbase + r0 + dr) * ld + off + c0) = v;
    }
}

__global__ __launch_bounds__(256, 2) void k_node(
    const float* __restrict__ x,
    const float* __restrict__ W1, const float* __restrict__ b1,
    const float* __restrict__ W2, const float* __restrict__ b2,
    const float* __restrict__ Wp1, const float* __restrict__ bp1,
    const float* __restrict__ WK, const float* __restrict__ bK,
    const float* __restrict__ WV, const float* __restrict__ bV,
    float* __restrict__ u, float* __restrict__ KV, float* __restrict__ zbase)
{
    __shared__ __align__(16) float bufA[64 * TS];
    __shared__ __align__(16) float bufB[64 * TS];
    __shared__ __align__(16) float w0[64 * TS];
    __shared__ __align__(16) float w1[64 * TS];
    int tid = threadIdx.x;
    if (tid < 33) {
        int i = blockIdx.x * 33 + tid;
        if (i < 16640) ((float4*)zbase)[i] = make_float4(0.f, 0.f, 0.f, 0.f);
    }
    int tx = tid & 15, ty = tid >> 4;
    int r0 = ty * 4, c0 = tx * 4;
    size_t rowbase = (size_t)blockIdx.x * 64;
    const float* xb = x + rowbase * 64;
    float4 a0 = ((const float4*)W1)[tid];
    float4 a1 = ((const float4*)W1)[tid + 256];
    float4 a2 = ((const float4*)W1)[tid + 512];
    float4 a3 = ((const float4*)W1)[tid + 768];
    float4 x0 = ((const float4*)xb)[tid];
    float4 x1 = ((const float4*)xb)[tid + 256];
    float4 x2 = ((const float4*)xb)[tid + 512];
    float4 x3 = ((const float4*)xb)[tid + 768];
    writeW(w0, tid, a0, a1, a2, a3);
    writeXT(bufA, tid, x0, x1, x2, x3);
    __syncthreads();
    float acc[4][4], accV[4][4];
    a0 = ((const float4*)W2)[tid];
    a1 = ((const float4*)W2)[tid + 256];
    a2 = ((const float4*)W2)[tid + 512];
    a3 = ((const float4*)W2)[tid + 768];
    gemm64(bufA, w0, b1, r0, c0, acc);
    outT_relu(bufB, r0, c0, acc);
    writeW(w1, tid, a0, a1, a2, a3);
    __syncthreads();
    a0 = ((const float4*)Wp1)[tid];
    a1 = ((const float4*)Wp1)[tid + 256];
    a2 = ((const float4*)Wp1)[tid + 512];
    a3 = ((const float4*)Wp1)[tid + 768];
    gemm64(bufB, w1, b2, r0, c0, acc);
    outT_relu(bufA, r0, c0, acc);
    writeW(w0, tid, a0, a1, a2, a3);
    __syncthreads();
    a0 = ((const float4*)WK)[tid];
    a1 = ((const float4*)WK)[tid + 256];
    a2 = ((const float4*)WK)[tid + 512];
    a3 = ((const float4*)WK)[tid + 768];
    float4 v0 = ((const float4*)WV)[tid];
    float4 v1 = ((const float4*)WV)[tid + 256];
    float4 v2 = ((const float4*)WV)[tid + 512];
    float4 v3 = ((const float4*)WV)[tid + 768];
    gemm64(bufA, w0, bp1, r0, c0, acc);
    outG2(u, rowbase, 64, 0, r0, c0, acc, true);
    writeW(w1, tid, a0, a1, a2, a3);
    writeW(bufB, tid, v0, v1, v2, v3);
    __syncthreads();
    gemm64x2(bufA, w1, bufB, bK, bV, r0, c0, acc, accV);
    outG2(KV, rowbase, 128, 0, r0, c0, acc, false);
    outG2(KV, rowbase, 128, 64, r0, c0, accV, false);
}

// ---------------------------------------------------------------------------
// k_msb: block per cluster. K/V chunks staged in LDS; GEMM encoding builds
// Msb[c] = relu(K)^T @ V; also Ksk/Krsum/Vsum/Lf and the full Q path -> Qk.
// ---------------------------------------------------------------------------
#define KSTR 72

__global__ __launch_bounds__(256, 4) void k_msb(
    const float* __restrict__ u, const float* __restrict__ KV,
    const int* __restrict__ mapper, const int* __restrict__ segoff,
    const float* __restrict__ Wp2, const float* __restrict__ bp2,
    const float* __restrict__ Wpo1, const float* __restrict__ bpo1,
    const float* __restrict__ Wpo2, const float* __restrict__ bpo2,
    float* __restrict__ Msb, float* __restrict__ Qk, float* __restrict__ Ksk,
    float* __restrict__ Krsum, float* __restrict__ Vsum, float* __restrict__ Lf)
{
    __shared__ __align__(16) float Kr[32 * KSTR];
    __shared__ __align__(16) float Vb[32 * KSTR];
    __shared__ int map_lds[32];
    __shared__ float sums[256];
    __shared__ float redu0[64], redu1[64], redu2[64];
    int c = blockIdx.x;
    int tid = threadIdx.x, j = tid & 63, g = tid >> 6;
    int tx = tid & 15, ty = tid >> 4;
    int r0 = ty * 4, c0 = tx * 4;
    int s0 = segoff[c], s1 = segoff[c + 1];
    sums[tid] = 0.f;
    float acc[4][4];
#pragma unroll
    for (int a = 0; a < 4; ++a)
#pragma unroll
        for (int b = 0; b < 4; ++b) acc[a][b] = 0.f;
    float qs = 0.f, ks = 0.f, krs = 0.f, vs = 0.f;
    __syncthreads();
    for (int sb = s0; sb < s1; sb += 32) {
        int clen = min(32, s1 - sb);
        __syncthreads();
        if (tid < clen) map_lds[tid] = mapper[sb + tid];
        __syncthreads();
        for (int p = tid; p < clen * 32; p += 256) {
            int e = p >> 5, q = p & 31;
            int m = map_lds[e];
            float4 v = *(const float4*)(KV + (size_t)m * 128 + q * 4);
            float* dst = (q < 16) ? &Kr[e * KSTR + q * 4] : &Vb[e * KSTR + (q - 16) * 4];
            *(float4*)dst = v;
        }
        __syncthreads();
#pragma unroll 4
        for (int s = 0; s < clen; ++s) {
            float4 a4 = *(const float4*)(&Kr[s * KSTR + r0]);
            float4 b4 = *(const float4*)(&Vb[s * KSTR + c0]);
            float ar0 = fmaxf(a4.x, 0.f), ar1 = fmaxf(a4.y, 0.f);
            float ar2 = fmaxf(a4.z, 0.f), ar3 = fmaxf(a4.w, 0.f);
            acc[0][0] = fmaf(ar0, b4.x, acc[0][0]); acc[0][1] = fmaf(ar0, b4.y, acc[0][1]);
            acc[0][2] = fmaf(ar0, b4.z, acc[0][2]); acc[0][3] = fmaf(ar0, b4.w, acc[0][3]);
            acc[1][0] = fmaf(ar1, b4.x, acc[1][0]); acc[1][1] = fmaf(ar1, b4.y, acc[1][1]);
            acc[1][2] = fmaf(ar1, b4.z, acc[1][2]); acc[1][3] = fmaf(ar1, b4.w, acc[1][3]);
            acc[2][0] = fmaf(ar2, b4.x, acc[2][0]); acc[2][1] = fmaf(ar2, b4.y, acc[2][1]);
            acc[2][2] = fmaf(ar2, b4.z, acc[2][2]); acc[2][3] = fmaf(ar2, b4.w, acc[2][3]);
            acc[3][0] = fmaf(ar3, b4.x, acc[3][0]); acc[3][1] = fmaf(ar3, b4.y, acc[3][1]);
            acc[3][2] = fmaf(ar3, b4.z, acc[3][2]); acc[3][3] = fmaf(ar3, b4.w, acc[3][3]);
        }
        for (int s = g; s < clen; s += 4) {
            float kv = Kr[s * KSTR + j];
            ks += kv;
            krs += fmaxf(kv, 0.f);
            vs += Vb[s * KSTR + j];
            qs += u[(size_t)map_lds[s] * 64 + j];
        }
    }
    atomicAdd(&sums[j], qs);
    atomicAdd(&sums[64 + j], ks);
    atomicAdd(&sums[128 + j], krs);
    atomicAdd(&sums[192 + j], vs);
    size_t mb = (size_t)c * 4096;
#pragma unroll
    for (int a = 0; a < 4; ++a)
        *(float4*)(Msb + mb + (size_t)(r0 + a) * 64 + c0) =
            make_float4(acc[a][0], acc[a][1], acc[a][2], acc[a][3]);
    int L = s1 - s0;
    if (tid < 64) {
        redu0[tid] = (float)L * bp2[tid];
        redu1[tid] = bpo1[tid];
        redu2[tid] = bpo2[tid];
    }
    __syncthreads();
    float qsv = sums[j];
    float Lm = (float)(L > 0 ? L : 1);
    if (g == 0) {
        Ksk[c * 64 + j] = fmaxf(sums[64 + j] / Lm, 0.f);
        Krsum[c * 64 + j] = sums[128 + j];
        Vsum[c * 64 + j] = sums[192 + j];
        if (j == 0) Lf[c] = (float)L;
    }
    float p = 0.f;
#pragma unroll
    for (int t = 0; t < 16; ++t) {
        int i = g * 16 + t;
        p = fmaf(rdlane(qsv, i), Wp2[i * 64 + j], p);
    }
    atomicAdd(&redu0[j], p);
    __syncthreads();
    float q2 = redu0[j];
    p = 0.f;
#pragma unroll
    for (int t = 0; t < 16; ++t) {
        int i = g * 16 + t;
        p = fmaf(rdlane(q2, i), Wpo1[i * 64 + j], p);
    }
    atomicAdd(&redu1[j], p);
    __syncthreads();
    float tt = fmaxf(redu1[j], 0.f);
    p = 0.f;
#pragma unroll
    for (int t = 0; t < 16; ++t) {
        int i = g * 16 + t;
        p = fmaf(rdlane(tt, i), Wpo2[i * 64 + j], p);
    }
    atomicAdd(&redu2[j], p);
    __syncthreads();
    if (tid < 64) Qk[c * 64 + tid] = fmaxf(redu2[tid], 0.f);
}

// ---------------------------------------------------------------------------
// k_edges: block per source r. Finds its own edges by scanning row[] (L2-hot,
// coalesced) into an LDS list — no CSR. Msb[r] staged in LDS (stride 68);
// ea computed on the fly from deg. 4 waves edge-parallel.
// ---------------------------------------------------------------------------
#define MSTR 68

__global__ __launch_bounds__(256, 4) void k_edges(
    const float* __restrict__ Msb, const float* __restrict__ Qk,
    const float* __restrict__ Ksk, const float* __restrict__ Krsum,
    const float* __restrict__ Vsum, const float* __restrict__ Lf,
    const int* __restrict__ row, const int* __restrict__ col,
    const float* __restrict__ attr, const float* __restrict__ deg,
    const float* __restrict__ ab,
    float* __restrict__ H, float* __restrict__ den)
{
    __shared__ __align__(16) float msb[64 * MSTR];
    __shared__ int eids[128];
    __shared__ int ecnt;
    int r = blockIdx.x;
    int tid = threadIdx.x, j = tid & 63, g = tid >> 6;
    if (tid == 0) ecnt = 0;
    __syncthreads();
    // stage Msb[r] and scan the edge list concurrently
    size_t mb = (size_t)r * 4096;
    for (int p = tid; p < 1024; p += 256) {
        float4 v = *(const float4*)(Msb + mb + (size_t)p * 4);
        int i = p >> 4, j0 = (p & 15) * 4;
        *(float4*)(&msb[i * MSTR + j0]) = v;
    }
#pragma unroll 4
    for (int i = 0; i < 64; ++i) {
        int e = i * 256 + tid;
        if (row[e] == r) {
            int p = atomicAdd(&ecnt, 1);
            if (p < 128) eids[p] = e;
        }
    }
    float kskj = Ksk[r * 64 + j];
    float krj  = Krsum[r * 64 + j];
    float vsj  = Vsum[r * 64 + j];
    float Lr   = Lf[r];
    float dr   = deg[r];
    float dinvr = dr > 0.f ? 1.f / sqrtf(dr) : 0.f;
    float a0 = ab[0], a1 = ab[1];
    float sa2 = 1.f + expf(a1 - a0);
    float sb2 = 1.f + expf(a0 - a1);
    __syncthreads();
    int ne = min(ecnt, 128);
    int idx = g;
    if (idx >= ne) return;
    int e = eids[idx];
    int c = col[e];
    float at = attr[e];
    float dc = deg[c];
    float qv = Qk[c * 64 + j];
    while (true) {
        int cc = c; float atc = at, dcc = dc, qc = qv;
        int nidx = idx + 4;
        if (nidx < ne) {
            int e2 = eids[nidx];
            c = col[e2];
            at = attr[e2];
            dc = deg[c];
            qv = Qk[c * 64 + j];
        }
        float dinvc = dcc > 0.f ? 1.f / sqrtf(dcc) : 0.f;
        float wc = dinvr * atc * dinvc;
        float wj0 = 0.f, wj1 = 0.f, wj2 = 0.f, wj3 = 0.f;
#pragma unroll
        for (int t = 0; t < 16; ++t) {
            wj0 = fmaf(rdlane(qc, 4 * t + 0), msb[(4 * t + 0) * MSTR + j], wj0);
            wj1 = fmaf(rdlane(qc, 4 * t + 1), msb[(4 * t + 1) * MSTR + j], wj1);
            wj2 = fmaf(rdlane(qc, 4 * t + 2), msb[(4 * t + 2) * MSTR + j], wj2);
            wj3 = fmaf(rdlane(qc, 4 * t + 3), msb[(4 * t + 3) * MSTR + j], wj3);
        }
        float wjt = (wj0 + wj1) + (wj2 + wj3);
        float p1 = qc * kskj;
        float p2 = qc * krj;
#pragma unroll
        for (int o = 32; o > 0; o >>= 1) { p1 += __shfl_xor(p1, o); p2 += __shfl_xor(p2, o); }
        atomicAdd(&H[cc * 64 + j], wc * (sb2 * wjt + sa2 * p1 * vsj));
        if (j == 0) atomicAdd(&den[cc], wc * (sa2 * Lr * p1 + sb2 * p2));
        idx = nidx;
        if (idx >= ne) break;
    }
}

// ---------------------------------------------------------------------------
__global__ __launch_bounds__(64) void k_final(
    const float* __restrict__ H, const float* __restrict__ den,
    const float* __restrict__ Wc1, const float* __restrict__ bc1,
    const float* __restrict__ Wc2, const float* __restrict__ bc2,
    float* __restrict__ out)
{
    int bg = blockIdx.x;
    int j = threadIdx.x;
    float acc = 0.f;
    for (int p = 0; p < PP; ++p) {
        int c = bg * PP + p;
        acc += H[c * 64 + j] / (den[c] + 1e-6f);
    }
    float g = acc * (1.f / (float)PP);
    int m = j & 31;
    float a1 = bc1[m];
#pragma unroll
    for (int i = 0; i < 64; ++i) a1 = fmaf(rdlane(g, i), Wc1[i * 32 + m], a1);
    float c1 = fmaxf(a1, 0.f);
    int n = (j < NC) ? j : 0;
    float a2 = bc2[n];
#pragma unroll
    for (int i = 0; i < 32; ++i) a2 = fmaf(rdlane(c1, i), Wc2[i * NC + n], a2);
    if (j < NC) out[bg * NC + j] = a2;
}

// ---------------------------------------------------------------------------
extern "C" void kernel_launch(void* const* d_in, const int* in_sizes, int n_in,
                              void* d_out, int out_size, void* d_ws, size_t ws_size,
                              hipStream_t stream)
{
    const float* x      = (const float*)d_in[0];
    const int*   mapper = (const int*)d_in[1];
    const int*   batch  = (const int*)d_in[2];
    const int*   row    = (const int*)d_in[3];
    const int*   col    = (const int*)d_in[4];
    const float* attr   = (const float*)d_in[5];
    const float* W_in1  = (const float*)d_in[6];
    const float* b_in1  = (const float*)d_in[7];
    const float* W_in2  = (const float*)d_in[8];
    const float* b_in2  = (const float*)d_in[9];
    const float* W_pre1 = (const float*)d_in[10];
    const float* b_pre1 = (const float*)d_in[11];
    const float* W_pre2 = (const float*)d_in[12];
    const float* b_pre2 = (const float*)d_in[13];
    const float* W_post1= (const float*)d_in[14];
    const float* b_post1= (const float*)d_in[15];
    const float* W_post2= (const float*)d_in[16];
    const float* b_post2= (const float*)d_in[17];
    const float* W_K    = (const float*)d_in[18];
    const float* b_K    = (const float*)d_in[19];
    const float* W_V    = (const float*)d_in[20];
    const float* b_V    = (const float*)d_in[21];
    const float* alpha_beta = (const float*)d_in[22];
    const float* W_c1   = (const float*)d_in[23];
    const float* b_c1   = (const float*)d_in[24];
    const float* W_c2   = (const float*)d_in[25];
    const float* b_c2   = (const float*)d_in[26];

    float* ws = (float*)d_ws;
    float* u     = ws;                        // N*64
    float* KV    = u     + (size_t)NN * 64;   // N*128
    float* Qk    = KV    + (size_t)NN * 128;  // C*64
    float* Msb   = Qk    + (size_t)CC * 64;   // C*4096
    float* Ksk   = Msb   + (size_t)CC * 4096; // C*64
    float* Krsum = Ksk   + (size_t)CC * 64;   // C*64
    float* Vsum  = Krsum + (size_t)CC * 64;   // C*64
    float* Lf    = Vsum  + (size_t)CC * 64;   // C
    float* deg   = Lf    + (size_t)CC;        // C
    // --- zeroed by k_node: H (C*64) + den (C) = 66560 floats = 16640 float4 ---
    float* H     = deg   + (size_t)CC;        // C*64
    float* den   = H     + (size_t)CC * 64;   // C
    int*  segoff = (int*)(den + (size_t)CC);  // C+1

    k_degseg<<<192, 256, 0, stream>>>(row, attr, batch, deg, segoff);
    k_node<<<NN / 64, 256, 0, stream>>>(x, W_in1, b_in1, W_in2, b_in2,
                                        W_pre1, b_pre1, W_K, b_K, W_V, b_V, u, KV, H);
    k_msb<<<CC, 256, 0, stream>>>(u, KV, mapper, segoff,
                                  W_pre2, b_pre2, W_post1, b_post1,
                                  W_post2, b_post2,
                                  Msb, Qk, Ksk, Krsum, Vsum, Lf);
    k_edges<<<CC, 256, 0, stream>>>(Msb, Qk, Ksk, Krsum, Vsum, Lf, row, col,
                                    attr, deg, alpha_beta, H, den);
    k_final<<<BB, 64, 0, stream>>>(H, den, W_c1, b_c1, W_c2, b_c2, (float*)d_out);
}

// Round 9
// 89.026 us; speedup vs baseline: 1.5192x; 1.2020x over previous
//
#include <hip/hip_runtime.h>
#include <math.h>

constexpr int NN = 32768;   // nodes
constexpr int SS = 32768;   // subgraph-node entries
constexpr int CC = 1024;    // clusters
constexpr int EE = 16384;   // coarsen edges
constexpr int BB = 16;      // graphs
constexpr int PP = 64;      // patches per graph
constexpr int NC = 10;      // classes

__device__ __forceinline__ float rdlane(float v, int l) {
    return __int_as_float(__builtin_amdgcn_readlane(__float_as_int(v), l));
}

// ---------------------------------------------------------------------------
// k_node: fused per-node dense chain + ALL preprocessing folded in:
//   blocks 0..63  : deg[16b..16b+16) via LDS accumulate over the edge stream
//   blocks 64..191: segoff boundary-writes over sorted batch
//   all blocks    : zero slice of H/den; 64-row tile of the dense chain
//     t1=relu(x@W1+b1); h=relu(t1@W2+b2); u=relu(h@Wp1+bp1)->u; K,V->KV
// ---------------------------------------------------------------------------
#define TS 68

__device__ __forceinline__ void gemm64(const float* A, const float* W,
                                       const float* __restrict__ bias,
                                       int r0, int c0, float acc[4][4])
{
#pragma unroll
    for (int dc = 0; dc < 4; ++dc) {
        float bv = bias[c0 + dc];
        acc[0][dc] = bv; acc[1][dc] = bv; acc[2][dc] = bv; acc[3][dc] = bv;
    }
#pragma unroll 16
    for (int k = 0; k < 64; ++k) {
        float4 av = *(const float4*)(A + k * TS + r0);
        float4 wv = *(const float4*)(W + k * TS + c0);
        acc[0][0] = fmaf(av.x, wv.x, acc[0][0]); acc[0][1] = fmaf(av.x, wv.y, acc[0][1]);
        acc[0][2] = fmaf(av.x, wv.z, acc[0][2]); acc[0][3] = fmaf(av.x, wv.w, acc[0][3]);
        acc[1][0] = fmaf(av.y, wv.x, acc[1][0]); acc[1][1] = fmaf(av.y, wv.y, acc[1][1]);
        acc[1][2] = fmaf(av.y, wv.z, acc[1][2]); acc[1][3] = fmaf(av.y, wv.w, acc[1][3]);
        acc[2][0] = fmaf(av.z, wv.x, acc[2][0]); acc[2][1] = fmaf(av.z, wv.y, acc[2][1]);
        acc[2][2] = fmaf(av.z, wv.z, acc[2][2]); acc[2][3] = fmaf(av.z, wv.w, acc[2][3]);
        acc[3][0] = fmaf(av.w, wv.x, acc[3][0]); acc[3][1] = fmaf(av.w, wv.y, acc[3][1]);
        acc[3][2] = fmaf(av.w, wv.z, acc[3][2]); acc[3][3] = fmaf(av.w, wv.w, acc[3][3]);
    }
}

__device__ __forceinline__ void gemm64x2(const float* A, const float* Wa, const float* Wb,
                                         const float* __restrict__ bias1,
                                         const float* __restrict__ bias2,
                                         int r0, int c0, float acc1[4][4], float acc2[4][4])
{
#pragma unroll
    for (int dc = 0; dc < 4; ++dc) {
        float bv1 = bias1[c0 + dc], bv2 = bias2[c0 + dc];
#pragma unroll
        for (int dr = 0; dr < 4; ++dr) { acc1[dr][dc] = bv1; acc2[dr][dc] = bv2; }
    }
#pragma unroll 8
    for (int k = 0; k < 64; ++k) {
        float4 av = *(const float4*)(A + k * TS + r0);
        float4 w1 = *(const float4*)(Wa + k * TS + c0);
        float4 w2 = *(const float4*)(Wb + k * TS + c0);
        float ar[4] = {av.x, av.y, av.z, av.w};
        float u1[4] = {w1.x, w1.y, w1.z, w1.w};
        float u2[4] = {w2.x, w2.y, w2.z, w2.w};
#pragma unroll
        for (int dr = 0; dr < 4; ++dr)
#pragma unroll
            for (int dc = 0; dc < 4; ++dc) {
                acc1[dr][dc] = fmaf(ar[dr], u1[dc], acc1[dr][dc]);
                acc2[dr][dc] = fmaf(ar[dr], u2[dc], acc2[dr][dc]);
            }
    }
}

__device__ __forceinline__ void writeW(float* dst, int tid,
                                       float4 a, float4 b, float4 c, float4 d)
{
    int colq = (tid & 15) * 4;
    int rb = tid >> 4;
    *(float4*)(dst + (rb     ) * TS + colq) = a;
    *(float4*)(dst + (rb + 16) * TS + colq) = b;
    *(float4*)(dst + (rb + 32) * TS + colq) = c;
    *(float4*)(dst + (rb + 48) * TS + colq) = d;
}

__device__ __forceinline__ void writeXT(float* dst, int tid,
                                        float4 a, float4 b, float4 c, float4 d)
{
    int rb = (tid * 4) & 63;
    int cb = tid >> 4;
    dst[(rb + 0) * TS + cb     ] = a.x;
    dst[(rb + 1) * TS + cb     ] = a.y;
    dst[(rb + 2) * TS + cb     ] = a.z;
    dst[(rb + 3) * TS + cb     ] = a.w;
    dst[(rb + 0) * TS + cb + 16] = b.x;
    dst[(rb + 1) * TS + cb + 16] = b.y;
    dst[(rb + 2) * TS + cb + 16] = b.z;
    dst[(rb + 3) * TS + cb + 16] = b.w;
    dst[(rb + 0) * TS + cb + 32] = c.x;
    dst[(rb + 1) * TS + cb + 32] = c.y;
    dst[(rb + 2) * TS + cb + 32] = c.z;
    dst[(rb + 3) * TS + cb + 32] = c.w;
    dst[(rb + 0) * TS + cb + 48] = d.x;
    dst[(rb + 1) * TS + cb + 48] = d.y;
    dst[(rb + 2) * TS + cb + 48] = d.z;
    dst[(rb + 3) * TS + cb + 48] = d.w;
}

__device__ __forceinline__ void outT_relu(float* dst, int r0, int c0, float acc[4][4])
{
#pragma unroll
    for (int dc = 0; dc < 4; ++dc) {
        *(float4*)(dst + (c0 + dc) * TS + r0) =
            make_float4(fmaxf(acc[0][dc], 0.f), fmaxf(acc[1][dc], 0.f),
                        fmaxf(acc[2][dc], 0.f), fmaxf(acc[3][dc], 0.f));
    }
}

__device__ __forceinline__ void outG2(float* __restrict__ dst, size_t rowbase, int ld,
                                      int off, int r0, int c0, float acc[4][4], bool dorelu)
{
#pragma unroll
    for (int dr = 0; dr < 4; ++dr) {
        float4 v = make_float4(acc[dr][0], acc[dr][1], acc[dr][2], acc[dr][3]);
        if (dorelu) {
            v.x = fmaxf(v.x, 0.f); v.y = fmaxf(v.y, 0.f);
            v.z = fmaxf(v.z, 0.f); v.w = fmaxf(v.w, 0.f);
        }
        *(float4*)(dst + (rowbase + r0 + dr) * ld + off + c0) = v;
    }
}

__global__ __launch_bounds__(256, 2) void k_node(
    const float* __restrict__ x,
    const int* __restrict__ row, const float* __restrict__ attr,
    const int* __restrict__ batch,
    const float* __restrict__ W1, const float* __restrict__ b1,
    const float* __restrict__ W2, const float* __restrict__ b2,
    const float* __restrict__ Wp1, const float* __restrict__ bp1,
    const float* __restrict__ WK, const float* __restrict__ bK,
    const float* __restrict__ WV, const float* __restrict__ bV,
    float* __restrict__ u, float* __restrict__ KV,
    float* __restrict__ deg, int* __restrict__ segoff, float* __restrict__ zbase)
{
    __shared__ __align__(16) float bufA[64 * TS];
    __shared__ __align__(16) float bufB[64 * TS];
    __shared__ __align__(16) float w0[64 * TS];
    __shared__ __align__(16) float w1[64 * TS];
    __shared__ float ldeg[16];
    int tid = threadIdx.x;
    int b = blockIdx.x;
    // zero H/den (16640 float4 over 512 blocks)
    if (tid < 33) {
        int i = b * 33 + tid;
        if (i < 16640) ((float4*)zbase)[i] = make_float4(0.f, 0.f, 0.f, 0.f);
    }
    // folded prep
    if (b < 64) {
        if (tid < 16) ldeg[tid] = 0.f;
        __syncthreads();
        int lo = b * 16;
#pragma unroll 4
        for (int i = 0; i < 64; ++i) {
            int e = i * 256 + tid;
            int r = row[e];
            unsigned d = (unsigned)(r - lo);
            if (d < 16u) atomicAdd(&ldeg[d], attr[e]);
        }
        __syncthreads();
        if (tid < 16) deg[lo + tid] = ldeg[tid];
    } else if (b < 192) {
        int t = (b - 64) * 256 + tid;          // covers [0, SS)
        int cur = batch[t];
        int prev = (t == 0) ? -1 : batch[t - 1];
        for (int c = prev + 1; c <= cur; ++c) segoff[c] = t;
        if (t == SS - 1)
            for (int c = cur + 1; c <= CC; ++c) segoff[c] = SS;
    }
    // dense chain
    int tx = tid & 15, ty = tid >> 4;
    int r0 = ty * 4, c0 = tx * 4;
    size_t rowbase = (size_t)b * 64;
    const float* xb = x + rowbase * 64;
    float4 a0 = ((const float4*)W1)[tid];
    float4 a1 = ((const float4*)W1)[tid + 256];
    float4 a2 = ((const float4*)W1)[tid + 512];
    float4 a3 = ((const float4*)W1)[tid + 768];
    float4 x0 = ((const float4*)xb)[tid];
    float4 x1 = ((const float4*)xb)[tid + 256];
    float4 x2 = ((const float4*)xb)[tid + 512];
    float4 x3 = ((const float4*)xb)[tid + 768];
    writeW(w0, tid, a0, a1, a2, a3);
    writeXT(bufA, tid, x0, x1, x2, x3);
    __syncthreads();
    float acc[4][4], accV[4][4];
    a0 = ((const float4*)W2)[tid];
    a1 = ((const float4*)W2)[tid + 256];
    a2 = ((const float4*)W2)[tid + 512];
    a3 = ((const float4*)W2)[tid + 768];
    gemm64(bufA, w0, b1, r0, c0, acc);
    outT_relu(bufB, r0, c0, acc);
    writeW(w1, tid, a0, a1, a2, a3);
    __syncthreads();
    a0 = ((const float4*)Wp1)[tid];
    a1 = ((const float4*)Wp1)[tid + 256];
    a2 = ((const float4*)Wp1)[tid + 512];
    a3 = ((const float4*)Wp1)[tid + 768];
    gemm64(bufB, w1, b2, r0, c0, acc);
    outT_relu(bufA, r0, c0, acc);
    writeW(w0, tid, a0, a1, a2, a3);
    __syncthreads();
    a0 = ((const float4*)WK)[tid];
    a1 = ((const float4*)WK)[tid + 256];
    a2 = ((const float4*)WK)[tid + 512];
    a3 = ((const float4*)WK)[tid + 768];
    float4 v0 = ((const float4*)WV)[tid];
    float4 v1 = ((const float4*)WV)[tid + 256];
    float4 v2 = ((const float4*)WV)[tid + 512];
    float4 v3 = ((const float4*)WV)[tid + 768];
    gemm64(bufA, w0, bp1, r0, c0, acc);
    outG2(u, rowbase, 64, 0, r0, c0, acc, true);
    writeW(w1, tid, a0, a1, a2, a3);
    writeW(bufB, tid, v0, v1, v2, v3);
    __syncthreads();
    gemm64x2(bufA, w1, bufB, bK, bV, r0, c0, acc, accV);
    outG2(KV, rowbase, 128, 0, r0, c0, acc, false);
    outG2(KV, rowbase, 128, 64, r0, c0, accV, false);
}

// ---------------------------------------------------------------------------
// k_qk: per-cluster Q path: Qs=(sum u[mapper])@Wp2 + L*bp2;
//       Qk = relu(relu(Qs@Wpo1+bpo1)@Wpo2+bpo2).
// 4 waves: gather 4-way; matvecs as 16-row partial slices + LDS reduce.
// ---------------------------------------------------------------------------
__global__ __launch_bounds__(256, 4) void k_qk(
    const float* __restrict__ u, const int* __restrict__ mapper,
    const int* __restrict__ segoff,
    const float* __restrict__ Wp2, const float* __restrict__ bp2,
    const float* __restrict__ Wpo1, const float* __restrict__ bpo1,
    const float* __restrict__ Wpo2, const float* __restrict__ bpo2,
    float* __restrict__ Qk)
{
    __shared__ float accs[4][64];
    int c = blockIdx.x;
    int tid = threadIdx.x, j = tid & 63, g = tid >> 6;
    int s0 = segoff[c], s1 = segoff[c + 1];
    float L = (float)(s1 - s0);
    if (tid < 64) {
        accs[0][tid] = 0.f;
        accs[1][tid] = L * bp2[tid];
        accs[2][tid] = bpo1[tid];
        accs[3][tid] = bpo2[tid];
    }
    __syncthreads();
    float us = 0.f;
    for (int s = s0 + g; s < s1; s += 4) us += u[(size_t)mapper[s] * 64 + j];
    atomicAdd(&accs[0][j], us);
    __syncthreads();
    float usv = accs[0][j];
    float p = 0.f;
#pragma unroll
    for (int t = 0; t < 16; ++t) {
        int i = g * 16 + t;
        p = fmaf(rdlane(usv, i), Wp2[i * 64 + j], p);
    }
    atomicAdd(&accs[1][j], p);
    __syncthreads();
    float qs = accs[1][j];
    p = 0.f;
#pragma unroll
    for (int t = 0; t < 16; ++t) {
        int i = g * 16 + t;
        p = fmaf(rdlane(qs, i), Wpo1[i * 64 + j], p);
    }
    atomicAdd(&accs[2][j], p);
    __syncthreads();
    float tv = fmaxf(accs[2][j], 0.f);
    p = 0.f;
#pragma unroll
    for (int t = 0; t < 16; ++t) {
        int i = g * 16 + t;
        p = fmaf(rdlane(tv, i), Wpo2[i * 64 + j], p);
    }
    atomicAdd(&accs[3][j], p);
    __syncthreads();
    if (g == 0) Qk[c * 64 + j] = fmaxf(accs[3][j], 0.f);
}

// ---------------------------------------------------------------------------
// k_msbedge: block per source cluster c. Build Msb = relu(K)^T @ V in
// registers (GEMM encoding), deposit into LDS (never global), then scatter
// over this cluster's out-edges (found by scanning row[], no CSR).
// ---------------------------------------------------------------------------
#define KSTR 72
#define MSTR 68

__global__ __launch_bounds__(256, 4) void k_msbedge(
    const float* __restrict__ KV, const int* __restrict__ mapper,
    const int* __restrict__ segoff, const float* __restrict__ Qk,
    const int* __restrict__ row, const int* __restrict__ col,
    const float* __restrict__ attr, const float* __restrict__ deg,
    const float* __restrict__ ab,
    float* __restrict__ H, float* __restrict__ den)
{
    __shared__ __align__(16) float Kr[32 * KSTR];
    __shared__ __align__(16) float Vb[32 * KSTR];
    __shared__ __align__(16) float msb[64 * MSTR];
    __shared__ int map_lds[32];
    __shared__ float sums[192];
    __shared__ int eids[128];
    __shared__ int ecnt;
    int c = blockIdx.x;
    int tid = threadIdx.x, j = tid & 63, g = tid >> 6;
    int tx = tid & 15, ty = tid >> 4;
    int r0 = ty * 4, c0 = tx * 4;
    if (tid == 0) ecnt = 0;
    if (tid < 192) sums[tid] = 0.f;
    __syncthreads();
    // edge scan first (also lets empty blocks bail before the build)
#pragma unroll 4
    for (int i = 0; i < 64; ++i) {
        int e = i * 256 + tid;
        if (row[e] == c) {
            int p = atomicAdd(&ecnt, 1);
            if (p < 128) eids[p] = e;
        }
    }
    __syncthreads();
    int ne = min(ecnt, 128);
    if (ne == 0) return;
    // build phase
    int s0 = segoff[c], s1 = segoff[c + 1];
    float acc[4][4];
#pragma unroll
    for (int a = 0; a < 4; ++a)
#pragma unroll
        for (int bq = 0; bq < 4; ++bq) acc[a][bq] = 0.f;
    float ks = 0.f, krs = 0.f, vs = 0.f;
    for (int sb = s0; sb < s1; sb += 32) {
        int clen = min(32, s1 - sb);
        __syncthreads();
        if (tid < clen) map_lds[tid] = mapper[sb + tid];
        __syncthreads();
        for (int p = tid; p < clen * 32; p += 256) {
            int e = p >> 5, q = p & 31;
            int m = map_lds[e];
            float4 v = *(const float4*)(KV + (size_t)m * 128 + q * 4);
            float* dst = (q < 16) ? &Kr[e * KSTR + q * 4] : &Vb[e * KSTR + (q - 16) * 4];
            *(float4*)dst = v;
        }
        __syncthreads();
#pragma unroll 4
        for (int s = 0; s < clen; ++s) {
            float4 a4 = *(const float4*)(&Kr[s * KSTR + r0]);
            float4 b4 = *(const float4*)(&Vb[s * KSTR + c0]);
            float ar0 = fmaxf(a4.x, 0.f), ar1 = fmaxf(a4.y, 0.f);
            float ar2 = fmaxf(a4.z, 0.f), ar3 = fmaxf(a4.w, 0.f);
            acc[0][0] = fmaf(ar0, b4.x, acc[0][0]); acc[0][1] = fmaf(ar0, b4.y, acc[0][1]);
            acc[0][2] = fmaf(ar0, b4.z, acc[0][2]); acc[0][3] = fmaf(ar0, b4.w, acc[0][3]);
            acc[1][0] = fmaf(ar1, b4.x, acc[1][0]); acc[1][1] = fmaf(ar1, b4.y, acc[1][1]);
            acc[1][2] = fmaf(ar1, b4.z, acc[1][2]); acc[1][3] = fmaf(ar1, b4.w, acc[1][3]);
            acc[2][0] = fmaf(ar2, b4.x, acc[2][0]); acc[2][1] = fmaf(ar2, b4.y, acc[2][1]);
            acc[2][2] = fmaf(ar2, b4.z, acc[2][2]); acc[2][3] = fmaf(ar2, b4.w, acc[2][3]);
            acc[3][0] = fmaf(ar3, b4.x, acc[3][0]); acc[3][1] = fmaf(ar3, b4.y, acc[3][1]);
            acc[3][2] = fmaf(ar3, b4.z, acc[3][2]); acc[3][3] = fmaf(ar3, b4.w, acc[3][3]);
        }
        for (int s = g; s < clen; s += 4) {
            float kv = Kr[s * KSTR + j];
            ks += kv;
            krs += fmaxf(kv, 0.f);
            vs += Vb[s * KSTR + j];
        }
    }
    // deposit Msb into LDS + reduce sums
#pragma unroll
    for (int a = 0; a < 4; ++a)
        *(float4*)(&msb[(r0 + a) * MSTR + c0]) =
            make_float4(acc[a][0], acc[a][1], acc[a][2], acc[a][3]);
    atomicAdd(&sums[j], ks);
    atomicAdd(&sums[64 + j], krs);
    atomicAdd(&sums[128 + j], vs);
    __syncthreads();
    int L = s1 - s0;
    float Lr = (float)L;
    float Lm = (float)(L > 0 ? L : 1);
    float kskj = fmaxf(sums[j] / Lm, 0.f);
    float krj  = sums[64 + j];
    float vsj  = sums[128 + j];
    float dr   = deg[c];
    float dinvr = dr > 0.f ? 1.f / sqrtf(dr) : 0.f;
    float a0 = ab[0], a1 = ab[1];
    float sa2 = 1.f + expf(a1 - a0);   // 1/softmax0
    float sb2 = 1.f + expf(a0 - a1);   // 1/softmax1
    // edge phase: 4 waves, each every 4th edge
    int idx = g;
    if (idx >= ne) return;
    int e = eids[idx];
    int cdst = col[e];
    float at = attr[e];
    float dc = deg[cdst];
    float qv = Qk[cdst * 64 + j];
    while (true) {
        int cc = cdst; float atc = at, dcc = dc, qc = qv;
        int nidx = idx + 4;
        if (nidx < ne) {
            int e2 = eids[nidx];
            cdst = col[e2];
            at = attr[e2];
            dc = deg[cdst];
            qv = Qk[cdst * 64 + j];
        }
        float dinvc = dcc > 0.f ? 1.f / sqrtf(dcc) : 0.f;
        float wc = dinvr * atc * dinvc;
        float wj0 = 0.f, wj1 = 0.f, wj2 = 0.f, wj3 = 0.f;
#pragma unroll
        for (int t = 0; t < 16; ++t) {
            wj0 = fmaf(rdlane(qc, 4 * t + 0), msb[(4 * t + 0) * MSTR + j], wj0);
            wj1 = fmaf(rdlane(qc, 4 * t + 1), msb[(4 * t + 1) * MSTR + j], wj1);
            wj2 = fmaf(rdlane(qc, 4 * t + 2), msb[(4 * t + 2) * MSTR + j], wj2);
            wj3 = fmaf(rdlane(qc, 4 * t + 3), msb[(4 * t + 3) * MSTR + j], wj3);
        }
        float wjt = (wj0 + wj1) + (wj2 + wj3);
        float p1 = qc * kskj;
        float p2 = qc * krj;
#pragma unroll
        for (int o = 32; o > 0; o >>= 1) { p1 += __shfl_xor(p1, o); p2 += __shfl_xor(p2, o); }
        atomicAdd(&H[cc * 64 + j], wc * (sb2 * wjt + sa2 * p1 * vsj));
        if (j == 0) atomicAdd(&den[cc], wc * (sa2 * Lr * p1 + sb2 * p2));
        idx = nidx;
        if (idx >= ne) break;
    }
}

// ---------------------------------------------------------------------------
__global__ __launch_bounds__(64) void k_final(
    const float* __restrict__ H, const float* __restrict__ den,
    const float* __restrict__ Wc1, const float* __restrict__ bc1,
    const float* __restrict__ Wc2, const float* __restrict__ bc2,
    float* __restrict__ out)
{
    int bg = blockIdx.x;
    int j = threadIdx.x;
    float acc = 0.f;
    for (int p = 0; p < PP; ++p) {
        int c = bg * PP + p;
        acc += H[c * 64 + j] / (den[c] + 1e-6f);
    }
    float g = acc * (1.f / (float)PP);
    int m = j & 31;
    float a1 = bc1[m];
#pragma unroll
    for (int i = 0; i < 64; ++i) a1 = fmaf(rdlane(g, i), Wc1[i * 32 + m], a1);
    float c1 = fmaxf(a1, 0.f);
    int n = (j < NC) ? j : 0;
    float a2 = bc2[n];
#pragma unroll
    for (int i = 0; i < 32; ++i) a2 = fmaf(rdlane(c1, i), Wc2[i * NC + n], a2);
    if (j < NC) out[bg * NC + j] = a2;
}

// ---------------------------------------------------------------------------
extern "C" void kernel_launch(void* const* d_in, const int* in_sizes, int n_in,
                              void* d_out, int out_size, void* d_ws, size_t ws_size,
                              hipStream_t stream)
{
    const float* x      = (const float*)d_in[0];
    const int*   mapper = (const int*)d_in[1];
    const int*   batch  = (const int*)d_in[2];
    const int*   row    = (const int*)d_in[3];
    const int*   col    = (const int*)d_in[4];
    const float* attr   = (const float*)d_in[5];
    const float* W_in1  = (const float*)d_in[6];
    const float* b_in1  = (const float*)d_in[7];
    const float* W_in2  = (const float*)d_in[8];
    const float* b_in2  = (const float*)d_in[9];
    const float* W_pre1 = (const float*)d_in[10];
    const float* b_pre1 = (const float*)d_in[11];
    const float* W_pre2 = (const float*)d_in[12];
    const float* b_pre2 = (const float*)d_in[13];
    const float* W_post1= (const float*)d_in[14];
    const float* b_post1= (const float*)d_in[15];
    const float* W_post2= (const float*)d_in[16];
    const float* b_post2= (const float*)d_in[17];
    const float* W_K    = (const float*)d_in[18];
    const float* b_K    = (const float*)d_in[19];
    const float* W_V    = (const float*)d_in[20];
    const float* b_V    = (const float*)d_in[21];
    const float* alpha_beta = (const float*)d_in[22];
    const float* W_c1   = (const float*)d_in[23];
    const float* b_c1   = (const float*)d_in[24];
    const float* W_c2   = (const float*)d_in[25];
    const float* b_c2   = (const float*)d_in[26];

    float* ws = (float*)d_ws;
    float* u     = ws;                        // N*64
    float* KV    = u     + (size_t)NN * 64;   // N*128
    float* Qk    = KV    + (size_t)NN * 128;  // C*64
    float* deg   = Qk    + (size_t)CC * 64;   // C
    // --- zeroed by k_node: H (C*64) + den (C) ---
    float* H     = deg   + (size_t)CC;        // C*64
    float* den   = H     + (size_t)CC * 64;   // C
    int*  segoff = (int*)(den + (size_t)CC);  // C+1

    k_node<<<NN / 64, 256, 0, stream>>>(x, row, attr, batch,
                                        W_in1, b_in1, W_in2, b_in2,
                                        W_pre1, b_pre1, W_K, b_K, W_V, b_V,
                                        u, KV, deg, segoff, H);
    k_qk<<<CC, 256, 0, stream>>>(u, mapper, segoff, W_pre2, b_pre2,
                                 W_post1, b_post1, W_post2, b_post2, Qk);
    k_msbedge<<<CC, 256, 0, stream>>>(KV, mapper, segoff, Qk, row, col,
                                      attr, deg, alpha_beta, H, den);
    k_final<<<BB, 64, 0, stream>>>(H, den, W_c1, b_c1, W_c2, b_c2, (float*)d_out);
}